// Round 1
// baseline (286.593 us; speedup 1.0000x reference)
//
#include <hip/hip_runtime.h>
#include <hip/hip_bf16.h>
#include <cstdint>

// ---------------------------------------------------------------------------
// SwinWindowTransformLayer: roll+add -> LayerNorm -> MLP(GELU) -> +x
// B=8, N=4096 (64x64), C=512, R=4, SHIFT=4. All inputs fp32; compute in bf16
// MFMA (16x16x32), fp32 accumulate.
// ---------------------------------------------------------------------------

#define BM 128
#define BN 128
#define BK 32

typedef short bf16x8 __attribute__((ext_vector_type(8)));
typedef float f32x4 __attribute__((ext_vector_type(4)));

#define GLOBAL_AS(p) ((__attribute__((address_space(1))) void*)(uintptr_t)(p))
#define LDS_AS(p)    ((__attribute__((address_space(3))) void*)(p))

static __device__ __forceinline__ ushort f2bf(float f) {
    uint32_t u = __float_as_uint(f);
    uint32_t r = (u + 0x7FFFu + ((u >> 16) & 1u)) >> 16;
    return (ushort)r;
}

static __device__ __forceinline__ float gelu_tanh(float v) {
    // JAX default gelu (approximate=True): 0.5*v*(1+tanh(0.79788456*(v+0.044715 v^3)))
    float u = 0.7978845608028654f * (v + 0.044715f * v * v * v);
    float e = __expf(2.0f * u);
    float th = 1.0f - 2.0f / (e + 1.0f);   // overflow-safe tanh
    return 0.5f * v * (1.0f + th);
}

// roll by (-4,-4) on a 64x64 grid: shifted[h][w] = grid[(h+4)%64][(w+4)%64]
static __device__ __forceinline__ int rolled_row(int row) {
    int b = row >> 12, n = row & 4095;
    int h = n >> 6, w = n & 63;
    int n2 = (((h + 4) & 63) << 6) | ((w + 4) & 63);
    return (b << 12) | n2;
}

// ---------------------------------------------------------------------------
// Kernel 1: x = in + roll(in); LayerNorm over C=512; write bf16 normed.
// One block (128 threads) per row.
// ---------------------------------------------------------------------------
__global__ __launch_bounds__(128)
void ln_kernel(const float* __restrict__ in, const float* __restrict__ gamma,
               const float* __restrict__ beta, ushort* __restrict__ normed) {
    const int row = blockIdx.x;
    const int t = threadIdx.x;
    const int row2 = rolled_row(row);

    const float4* p0 = (const float4*)(in + (size_t)row * 512);
    const float4* p1 = (const float4*)(in + (size_t)row2 * 512);
    float4 a = p0[t], c = p1[t];
    float x0 = a.x + c.x, x1 = a.y + c.y, x2 = a.z + c.z, x3 = a.w + c.w;

    float s = x0 + x1 + x2 + x3;
    float sq = x0 * x0 + x1 * x1 + x2 * x2 + x3 * x3;
#pragma unroll
    for (int o = 32; o > 0; o >>= 1) {
        s += __shfl_xor(s, o);
        sq += __shfl_xor(sq, o);
    }
    __shared__ float red[4];
    if ((t & 63) == 0) { red[(t >> 6) * 2] = s; red[(t >> 6) * 2 + 1] = sq; }
    __syncthreads();
    s = red[0] + red[2];
    sq = red[1] + red[3];
    float mu = s * (1.0f / 512.0f);
    float var = sq * (1.0f / 512.0f) - mu * mu;
    float rs = rsqrtf(var + 1e-6f);

    float4 g = ((const float4*)gamma)[t];
    float4 be = ((const float4*)beta)[t];
    ushort4 o4;
    o4.x = f2bf((x0 - mu) * rs * g.x + be.x);
    o4.y = f2bf((x1 - mu) * rs * g.y + be.y);
    o4.z = f2bf((x2 - mu) * rs * g.z + be.z);
    o4.w = f2bf((x3 - mu) * rs * g.w + be.w);
    ((ushort4*)(normed + (size_t)row * 512))[t] = o4;
}

// ---------------------------------------------------------------------------
// Kernel 2: transpose + cast fp32 [R][Ccols] -> bf16 [Ccols][R]
// ---------------------------------------------------------------------------
__global__ __launch_bounds__(256)
void transpose_cast(const float* __restrict__ src, ushort* __restrict__ dst,
                    int R, int Ccols) {
    __shared__ float tile[32][33];
    const int bx = blockIdx.x * 32;  // col
    const int by = blockIdx.y * 32;  // row
    const int tx = threadIdx.x, ty = threadIdx.y;  // 32x8
#pragma unroll
    for (int i = 0; i < 32; i += 8)
        tile[ty + i][tx] = src[(size_t)(by + ty + i) * Ccols + bx + tx];
    __syncthreads();
#pragma unroll
    for (int i = 0; i < 32; i += 8)
        dst[(size_t)(bx + ty + i) * R + by + tx] = f2bf(tile[tx][ty + i]);
}

// ---------------------------------------------------------------------------
// GEMM: C[M,N] = A[M,K] * Bt[N,K]^T (+bias)  bf16 in, fp32 acc
// EPI=0: out = bf16(gelu(acc + bias)) -> outH
// EPI=1: out = acc + bias + resid[row] + resid[rolled(row)] -> outF (fp32)
// 128x128 tile, BK=32, 256 threads (4 waves 2x2), 4x4 16x16x32 frags/wave.
// ---------------------------------------------------------------------------
template <int EPI>
__global__ __launch_bounds__(256)
void gemm_bt_kernel(const ushort* __restrict__ A, const ushort* __restrict__ Bt,
                    const float* __restrict__ bias, const float* __restrict__ resid,
                    ushort* __restrict__ outH, float* __restrict__ outF,
                    int M, int N, int K) {
    __shared__ ushort Asm[BM * BK];
    __shared__ ushort Bsm[BN * BK];

    const int t = threadIdx.x;
    const int w = t >> 6, l = t & 63;
    const int wr = w >> 1, wc = w & 1;
    const int brow = blockIdx.y * BM;
    const int bcol = blockIdx.x * BN;

    f32x4 acc[4][4] = {};

    // staging: 256 thr x 16B = 4KB/pass; 2 passes per 8KB tile
    const int arow = t >> 2;          // 0..63
    const int acol = (t & 3) * 8;     // element offset within BK
    const size_t aBase = (size_t)(brow + arow) * K + acol;
    const size_t bBase = (size_t)(bcol + arow) * K + acol;
    char* ldsA = (char*)Asm + w * 1024;   // wave-uniform dest base
    char* ldsB = (char*)Bsm + w * 1024;

    const int kb = (l >> 4) * 8;      // k offset of this lane's fragment
    const int rA = (l & 15);          // row-within-16

    for (int k0 = 0; k0 < K; k0 += BK) {
        __builtin_amdgcn_global_load_lds(GLOBAL_AS(A + aBase + k0), LDS_AS(ldsA), 16, 0, 0);
        __builtin_amdgcn_global_load_lds(GLOBAL_AS(A + aBase + (size_t)64 * K + k0), LDS_AS(ldsA + 4096), 16, 0, 0);
        __builtin_amdgcn_global_load_lds(GLOBAL_AS(Bt + bBase + k0), LDS_AS(ldsB), 16, 0, 0);
        __builtin_amdgcn_global_load_lds(GLOBAL_AS(Bt + bBase + (size_t)64 * K + k0), LDS_AS(ldsB + 4096), 16, 0, 0);
        __syncthreads();  // drains vmcnt -> LDS tiles complete

        bf16x8 aF[4], bF[4];
#pragma unroll
        for (int i = 0; i < 4; ++i)
            aF[i] = *(const bf16x8*)&Asm[(wr * 64 + i * 16 + rA) * BK + kb];
#pragma unroll
        for (int j = 0; j < 4; ++j)
            bF[j] = *(const bf16x8*)&Bsm[(wc * 64 + j * 16 + rA) * BK + kb];

#pragma unroll
        for (int i = 0; i < 4; ++i)
#pragma unroll
            for (int j = 0; j < 4; ++j)
                acc[i][j] = __builtin_amdgcn_mfma_f32_16x16x32_bf16(aF[i], bF[j], acc[i][j], 0, 0, 0);
        __syncthreads();  // protect LDS before next stage
    }

    // epilogue: D row = (l>>4)*4 + r, col = l&15 (within each 16x16 frag)
    const int cm = (l >> 4) * 4;
    const int cn = (l & 15);
    if (EPI == 0) {
#pragma unroll
        for (int i = 0; i < 4; ++i) {
#pragma unroll
            for (int j = 0; j < 4; ++j) {
                const int col = bcol + wc * 64 + j * 16 + cn;
                const float bv = bias[col];
#pragma unroll
                for (int r = 0; r < 4; ++r) {
                    const int row = brow + wr * 64 + i * 16 + cm + r;
                    outH[(size_t)row * N + col] = f2bf(gelu_tanh(acc[i][j][r] + bv));
                }
            }
        }
    } else {
#pragma unroll
        for (int i = 0; i < 4; ++i) {
#pragma unroll
            for (int r = 0; r < 4; ++r) {
                const int row = brow + wr * 64 + i * 16 + cm + r;
                const int row2 = rolled_row(row);
                const float* x0 = resid + (size_t)row * 512;
                const float* x1 = resid + (size_t)row2 * 512;
#pragma unroll
                for (int j = 0; j < 4; ++j) {
                    const int col = bcol + wc * 64 + j * 16 + cn;
                    outF[(size_t)row * N + col] = acc[i][j][r] + bias[col] + x0[col] + x1[col];
                }
            }
        }
    }
}

// ---------------------------------------------------------------------------
extern "C" void kernel_launch(void* const* d_in, const int* in_sizes, int n_in,
                              void* d_out, int out_size, void* d_ws, size_t ws_size,
                              hipStream_t stream) {
    const float* in = (const float*)d_in[0];
    const float* ln_g = (const float*)d_in[1];
    const float* ln_b = (const float*)d_in[2];
    const float* W1 = (const float*)d_in[3];
    const float* b1 = (const float*)d_in[4];
    const float* W2 = (const float*)d_in[5];
    const float* b2 = (const float*)d_in[6];
    float* out = (float*)d_out;

    char* ws = (char*)d_ws;
    ushort* normed = (ushort*)ws;                                  // 32 MB
    ushort* hbuf   = (ushort*)(ws + (size_t)32 * 1024 * 1024);     // 128 MB
    ushort* W1T    = (ushort*)(ws + (size_t)160 * 1024 * 1024);    // 2 MB [2048][512]
    ushort* W2T    = (ushort*)(ws + (size_t)162 * 1024 * 1024);    // 2 MB [512][2048]

    const int M = 32768;        // B*N rows
    const int C = 512, C4 = 2048;

    ln_kernel<<<M, 128, 0, stream>>>(in, ln_g, ln_b, normed);
    transpose_cast<<<dim3(C4 / 32, C / 32), dim3(32, 8), 0, stream>>>(W1, W1T, C, C4);
    transpose_cast<<<dim3(C / 32, C4 / 32), dim3(32, 8), 0, stream>>>(W2, W2T, C4, C);

    gemm_bt_kernel<0><<<dim3(C4 / BN, M / BM), 256, 0, stream>>>(
        normed, W1T, b1, nullptr, hbuf, nullptr, M, C4, C);
    gemm_bt_kernel<1><<<dim3(C / BN, M / BM), 256, 0, stream>>>(
        hbuf, W2T, b2, in, nullptr, out, M, C, C4);
}

// Round 2
// 251.945 us; speedup vs baseline: 1.1375x; 1.1375x over previous
//
#include <hip/hip_runtime.h>
#include <hip/hip_bf16.h>
#include <cstdint>
#include <cstddef>

// ---------------------------------------------------------------------------
// SwinWindowTransformLayer: roll+add -> LayerNorm -> MLP(GELU) -> +x
// Round 2: 256x256 8-phase GEMM (K-half units, 4-slot LDS rings, counted
// vmcnt(6), XOR-swizzled LDS, setprio) + LDS-repacked epilogues.
// ---------------------------------------------------------------------------

typedef short bf16x8 __attribute__((ext_vector_type(8)));
typedef float f32x4 __attribute__((ext_vector_type(4)));

#define GLOBAL_AS(p) ((__attribute__((address_space(1))) void*)(uintptr_t)(p))
#define LDS_AS(p)    ((__attribute__((address_space(3))) void*)(p))

static __device__ __forceinline__ ushort f2bf(float f) {
    uint32_t u = __float_as_uint(f);
    uint32_t r = (u + 0x7FFFu + ((u >> 16) & 1u)) >> 16;
    return (ushort)r;
}

static __device__ __forceinline__ float gelu_tanh(float v) {
    float u = 0.7978845608028654f * (v + 0.044715f * v * v * v);
    float e = __expf(2.0f * u);
    float th = 1.0f - 2.0f / (e + 1.0f);   // overflow-safe tanh
    return 0.5f * v * (1.0f + th);
}

// roll by (-4,-4) on a 64x64 grid: shifted[h][w] = grid[(h+4)%64][(w+4)%64]
static __device__ __forceinline__ int rolled_row(int row) {
    int b = row >> 12, n = row & 4095;
    int h = n >> 6, wv = n & 63;
    int n2 = (((h + 4) & 63) << 6) | ((wv + 4) & 63);
    return (b << 12) | n2;
}

#define SBAR() do { __builtin_amdgcn_sched_barrier(0); \
                    __builtin_amdgcn_s_barrier(); \
                    __builtin_amdgcn_sched_barrier(0); } while (0)

// ---------------------------------------------------------------------------
// Kernel 1: x = in + roll(in); LayerNorm over C=512; write bf16 normed.
// ---------------------------------------------------------------------------
__global__ __launch_bounds__(128)
void ln_kernel(const float* __restrict__ in, const float* __restrict__ gamma,
               const float* __restrict__ beta, ushort* __restrict__ normed) {
    const int row = blockIdx.x;
    const int t = threadIdx.x;
    const int row2 = rolled_row(row);

    const float4* p0 = (const float4*)(in + (size_t)row * 512);
    const float4* p1 = (const float4*)(in + (size_t)row2 * 512);
    float4 a = p0[t], c = p1[t];
    float x0 = a.x + c.x, x1 = a.y + c.y, x2 = a.z + c.z, x3 = a.w + c.w;

    float s = x0 + x1 + x2 + x3;
    float sq = x0 * x0 + x1 * x1 + x2 * x2 + x3 * x3;
#pragma unroll
    for (int o = 32; o > 0; o >>= 1) {
        s += __shfl_xor(s, o);
        sq += __shfl_xor(sq, o);
    }
    __shared__ float red[4];
    if ((t & 63) == 0) { red[(t >> 6) * 2] = s; red[(t >> 6) * 2 + 1] = sq; }
    __syncthreads();
    s = red[0] + red[2];
    sq = red[1] + red[3];
    float mu = s * (1.0f / 512.0f);
    float var = sq * (1.0f / 512.0f) - mu * mu;
    float rs = rsqrtf(var + 1e-6f);

    float4 g = ((const float4*)gamma)[t];
    float4 be = ((const float4*)beta)[t];
    ushort4 o4;
    o4.x = f2bf((x0 - mu) * rs * g.x + be.x);
    o4.y = f2bf((x1 - mu) * rs * g.y + be.y);
    o4.z = f2bf((x2 - mu) * rs * g.z + be.z);
    o4.w = f2bf((x3 - mu) * rs * g.w + be.w);
    ((ushort4*)(normed + (size_t)row * 512))[t] = o4;
}

// ---------------------------------------------------------------------------
// Kernel 2: transpose + cast fp32 [R][Ccols] -> bf16 [Ccols][R]
// ---------------------------------------------------------------------------
__global__ __launch_bounds__(256)
void transpose_cast(const float* __restrict__ src, ushort* __restrict__ dst,
                    int R, int Ccols) {
    __shared__ float tile[32][33];
    const int bx = blockIdx.x * 32;
    const int by = blockIdx.y * 32;
    const int tx = threadIdx.x, ty = threadIdx.y;
#pragma unroll
    for (int i = 0; i < 32; i += 8)
        tile[ty + i][tx] = src[(size_t)(by + ty + i) * Ccols + bx + tx];
    __syncthreads();
#pragma unroll
    for (int i = 0; i < 32; i += 8)
        dst[(size_t)(bx + ty + i) * R + by + tx] = f2bf(tile[tx][ty + i]);
}

// ---------------------------------------------------------------------------
// 8-phase 256x256 GEMM.  C = A[M,K] * Bt[N,K]^T, bf16 in / f32 acc.
// 512 threads = 8 waves (2M x 4N), per-wave C = 128x64 (8x4 16x16 frags).
// Units: [256 rows][32 k] bf16 = 16 KB (one MFMA k-step). 4-slot ring per
// matrix, 128 KB LDS total. Issue schedule: unit for tile t arrives 7 units
// (~2 tiles) early; vmcnt(6) at each tile boundary only.
// LDS swizzle: byte bits {4,5} ^= byte bits {8,9} (involution; applied on
// the pre-swizzled global source for global_load_lds, and on ds_read addr).
// EPI=0: h = bf16(gelu(acc+bias)), LDS-repacked coalesced store.
// EPI=1: out = acc + bias + resid[row] + resid[rolled(row)], f32, 2-half
//        LDS repack with coalesced residual gathers.
// ---------------------------------------------------------------------------
template <int EPI, int LOG2NCB>
__global__ __launch_bounds__(512, 2)
void gemm8p(const ushort* __restrict__ A, const ushort* __restrict__ Bt,
            const float* __restrict__ bias, const float* __restrict__ resid,
            ushort* __restrict__ outH, float* __restrict__ outF,
            int N, int K) {
    __shared__ __align__(16) char sm[131072];
    const int t = threadIdx.x;
    const int w = t >> 6, l = t & 63;
    const int wr = w >> 2, wc = w & 3;

    // XCD-aware swizzle (grid divisible by 8), cols fastest within a chunk
    const int nwg = gridDim.x;
    const int bid = blockIdx.x;
    const int swz = (bid & 7) * (nwg >> 3) + (bid >> 3);
    const int rb = swz >> LOG2NCB, cb = swz & ((1 << LOG2NCB) - 1);
    const int brow = rb << 8, bcol = cb << 8;

    // --- staging source (per thread). Unit chunk o = pass*8192 + t*16:
    // row = pass*128 + t/4, kchunk = (t&3) ^ ((t>>4)&3)  [inverse swizzle]
    const int kksw = (((t & 3) ^ ((t >> 4) & 3)) << 3);
    const size_t aOff0 = (size_t)(brow + (t >> 2)) * K + kksw;
    const size_t aOff1 = aOff0 + (size_t)128 * K;
    const size_t bOff0 = (size_t)(bcol + (t >> 2)) * K + kksw;
    const size_t bOff1 = bOff0 + (size_t)128 * K;
    char* const dA = (char*)sm + (w << 10);   // wave-uniform dest base
    char* const dB = dA + 65536;

    // --- fragment ds_read offsets: byte = row*64 + (l>>4)*16, swizzled.
    // row bits 2,3 == (l&15) bits 2,3  ->  per-lane constant XOR.
    const int xorv = ((l >> 2) & 3) << 4;
    const int preA = ((((wr << 7) + (l & 15)) << 6) + ((l >> 4) << 4)) ^ xorv;
    const int preB = 65536 + (((((wc << 6) + (l & 15)) << 6) + ((l >> 4) << 4)) ^ xorv);

    f32x4 acc[8][4] = {};
    bf16x8 aF[4], bF[4];

    auto issueA = [&](int tt, int kh, int slot) {
        const int kc = (tt << 6) + (kh << 5);
        char* d = dA + (slot << 14);
        __builtin_amdgcn_global_load_lds(GLOBAL_AS(A + aOff0 + kc), LDS_AS(d), 16, 0, 0);
        __builtin_amdgcn_global_load_lds(GLOBAL_AS(A + aOff1 + kc), LDS_AS(d + 8192), 16, 0, 0);
    };
    auto issueB = [&](int tt, int kh, int slot) {
        const int kc = (tt << 6) + (kh << 5);
        char* d = dB + (slot << 14);
        __builtin_amdgcn_global_load_lds(GLOBAL_AS(Bt + bOff0 + kc), LDS_AS(d), 16, 0, 0);
        __builtin_amdgcn_global_load_lds(GLOBAL_AS(Bt + bOff1 + kc), LDS_AS(d + 8192), 16, 0, 0);
    };
    auto rdA = [&](int slot, int mb) {
        const char* p = (const char*)sm + (slot << 14) + preA + (mb << 12);
        aF[0] = *(const bf16x8*)(p);
        aF[1] = *(const bf16x8*)(p + 1024);
        aF[2] = *(const bf16x8*)(p + 2048);
        aF[3] = *(const bf16x8*)(p + 3072);
    };
    auto rdB = [&](int slot) {
        const char* p = (const char*)sm + (slot << 14) + preB;
        bF[0] = *(const bf16x8*)(p);
        bF[1] = *(const bf16x8*)(p + 1024);
        bF[2] = *(const bf16x8*)(p + 2048);
        bF[3] = *(const bf16x8*)(p + 3072);
    };
    auto mfma16 = [&](int mb) {
        __builtin_amdgcn_s_setprio(1);
#pragma unroll
        for (int mf = 0; mf < 4; ++mf)
#pragma unroll
            for (int nf = 0; nf < 4; ++nf)
                acc[mb * 4 + mf][nf] = __builtin_amdgcn_mfma_f32_16x16x32_bf16(
                    aF[mf], bF[nf], acc[mb * 4 + mf][nf], 0, 0, 0);
        __builtin_amdgcn_s_setprio(0);
    };

    // --- prologue: units 0..6 (tile0 complete + 3 units of tile1)
    issueA(0, 0, 0); issueB(0, 0, 0);
    issueA(0, 1, 1); issueB(0, 1, 1);
    issueA(1, 0, 2); issueB(1, 0, 2);
    issueA(1, 1, 3);
    __builtin_amdgcn_sched_barrier(0);
    asm volatile("s_waitcnt vmcnt(6)" ::: "memory");
    SBAR();

    const int NT = K >> 6;
    for (int tt = 0; tt < NT; ++tt) {
        const int s0 = (tt & 1) << 1;
        // phase 0: kh=0, m-frags 0-3; issue B(tt+1, kh=1)
        rdA(s0, 0); rdB(s0);
        SBAR();
        if (tt + 1 < NT) issueB(tt + 1, 1, (s0 ^ 2) | 1);
        mfma16(0);
        SBAR();
        // phase 1: kh=0, m-frags 4-7 (reuse bF); issue A(tt+2, kh=0)
        rdA(s0, 1);
        SBAR();
        if (tt + 2 < NT) issueA(tt + 2, 0, s0);
        mfma16(1);
        SBAR();
        // phase 2: kh=1, m-frags 0-3; issue B(tt+2, kh=0)
        rdA(s0 + 1, 0); rdB(s0 + 1);
        SBAR();
        if (tt + 2 < NT) issueB(tt + 2, 0, s0);
        mfma16(0);
        SBAR();
        // phase 3: kh=1, m-frags 4-7; issue A(tt+2, kh=1)
        rdA(s0 + 1, 1);
        SBAR();
        if (tt + 2 < NT) issueA(tt + 2, 1, s0 + 1);
        mfma16(1);
        __builtin_amdgcn_sched_barrier(0);
        if (tt < NT - 2)       { asm volatile("s_waitcnt vmcnt(6)" ::: "memory"); }
        else if (tt == NT - 2) { asm volatile("s_waitcnt vmcnt(0)" ::: "memory"); }
        SBAR();   // publish next tile's units / protect LDS for epilogue
    }

    // ---------------- epilogue ----------------
    if constexpr (EPI == 0) {
        float bv[4];
#pragma unroll
        for (int nf = 0; nf < 4; ++nf)
            bv[nf] = bias[bcol + (wc << 6) + nf * 16 + (l & 15)];
#pragma unroll
        for (int mf = 0; mf < 8; ++mf)
#pragma unroll
            for (int nf = 0; nf < 4; ++nf)
#pragma unroll
                for (int r = 0; r < 4; ++r) {
                    int row = (wr << 7) + mf * 16 + ((l >> 4) << 2) + r;
                    int col = (wc << 6) + nf * 16 + (l & 15);
                    *(ushort*)(sm + row * 512 + col * 2) =
                        f2bf(gelu_tanh(acc[mf][nf][r] + bv[nf]));
                }
        SBAR();
        // coalesced: 8192 16B chunks, 16 per thread
#pragma unroll
        for (int k = 0; k < 16; ++k) {
            int c = t + (k << 9);
            int row = c >> 5, c8 = c & 31;
            int4 v = *(const int4*)(sm + ((size_t)c << 4));
            *(int4*)(outH + (size_t)(brow + row) * N + bcol + (c8 << 3)) = v;
        }
    } else {
        // two 128-row halves of f32 [128][256] = 128 KB each
#pragma unroll
        for (int h2 = 0; h2 < 2; ++h2) {
            if (wr == h2) {
#pragma unroll
                for (int mf = 0; mf < 8; ++mf)
#pragma unroll
                    for (int nf = 0; nf < 4; ++nf)
#pragma unroll
                        for (int r = 0; r < 4; ++r) {
                            int rl = mf * 16 + ((l >> 4) << 2) + r;
                            int col = (wc << 6) + nf * 16 + (l & 15);
                            *(float*)(sm + rl * 1024 + col * 4) = acc[mf][nf][r];
                        }
            }
            __syncthreads();
#pragma unroll
            for (int k = 0; k < 16; ++k) {
                int c = t + (k << 9);
                int row = c >> 6, c4 = c & 63;
                f32x4 v = *(const f32x4*)(sm + ((size_t)c << 4));
                int R = brow + (h2 << 7) + row;
                int col0 = bcol + (c4 << 2);
                f32x4 bb = *(const f32x4*)(bias + col0);
                f32x4 x0 = *(const f32x4*)(resid + (size_t)R * 512 + col0);
                f32x4 x1 = *(const f32x4*)(resid + (size_t)rolled_row(R) * 512 + col0);
                v = v + bb + x0 + x1;
                *(f32x4*)(outF + (size_t)R * N + col0) = v;
            }
            __syncthreads();
        }
    }
}

// ---------------------------------------------------------------------------
extern "C" void kernel_launch(void* const* d_in, const int* in_sizes, int n_in,
                              void* d_out, int out_size, void* d_ws, size_t ws_size,
                              hipStream_t stream) {
    const float* in = (const float*)d_in[0];
    const float* ln_g = (const float*)d_in[1];
    const float* ln_b = (const float*)d_in[2];
    const float* W1 = (const float*)d_in[3];
    const float* b1 = (const float*)d_in[4];
    const float* W2 = (const float*)d_in[5];
    const float* b2 = (const float*)d_in[6];
    float* out = (float*)d_out;

    char* ws = (char*)d_ws;
    ushort* normed = (ushort*)ws;                                  // 32 MB
    ushort* hbuf   = (ushort*)(ws + (size_t)32 * 1024 * 1024);     // 128 MB
    ushort* W1T    = (ushort*)(ws + (size_t)160 * 1024 * 1024);    // 2 MB [2048][512]
    ushort* W2T    = (ushort*)(ws + (size_t)162 * 1024 * 1024);    // 2 MB [512][2048]

    const int M = 32768;
    const int C = 512, C4 = 2048;

    ln_kernel<<<M, 128, 0, stream>>>(in, ln_g, ln_b, normed);
    transpose_cast<<<dim3(C4 / 32, C / 32), dim3(32, 8), 0, stream>>>(W1, W1T, C, C4);
    transpose_cast<<<dim3(C / 32, C4 / 32), dim3(32, 8), 0, stream>>>(W2, W2T, C4, C);

    // GEMM1: [32768,512] x [512,2048] -> gelu -> bf16 h.  grid 128x8=1024
    gemm8p<0, 3><<<dim3(1024), 512, 0, stream>>>(
        normed, W1T, b1, nullptr, hbuf, nullptr, C4, C);
    // GEMM2: [32768,2048] x [2048,512] + bias + x -> out.  grid 128x2=256
    gemm8p<1, 1><<<dim3(256), 512, 0, stream>>>(
        hbuf, W2T, b2, in, nullptr, out, C, C4);
}

// Round 3
// 241.979 us; speedup vs baseline: 1.1844x; 1.0412x over previous
//
#include <hip/hip_runtime.h>
#include <hip/hip_bf16.h>
#include <cstdint>
#include <cstddef>

// ---------------------------------------------------------------------------
// SwinWindowTransformLayer: roll+add -> LayerNorm -> MLP(GELU) -> +x
// Round 3: persistent-block 8-phase GEMM. Both GEMMs = grid 256, 32 K-tiles
// linear stream per block (GEMM1: 4 output tiles x 8, GEMM2: 1 x 32), ring
// prefetch flows across output-tile boundaries, LDS-free direct-store
// epilogues overlapped with the next tile's K-loop.
// ---------------------------------------------------------------------------

typedef short bf16x8 __attribute__((ext_vector_type(8)));
typedef float f32x4 __attribute__((ext_vector_type(4)));

#define GLOBAL_AS(p) ((__attribute__((address_space(1))) void*)(uintptr_t)(p))
#define LDS_AS(p)    ((__attribute__((address_space(3))) void*)(p))

static __device__ __forceinline__ ushort f2bf(float f) {
    uint32_t u = __float_as_uint(f);
    uint32_t r = (u + 0x7FFFu + ((u >> 16) & 1u)) >> 16;
    return (ushort)r;
}

static __device__ __forceinline__ float gelu_tanh(float v) {
    float u = 0.7978845608028654f * (v + 0.044715f * v * v * v);
    float e = __expf(2.0f * u);
    float th = 1.0f - 2.0f / (e + 1.0f);   // overflow-safe tanh
    return 0.5f * v * (1.0f + th);
}

// roll by (-4,-4) on a 64x64 grid: shifted[h][w] = grid[(h+4)%64][(w+4)%64]
static __device__ __forceinline__ int rolled_row(int row) {
    int b = row >> 12, n = row & 4095;
    int h = n >> 6, wv = n & 63;
    int n2 = (((h + 4) & 63) << 6) | ((wv + 4) & 63);
    return (b << 12) | n2;
}

#define SBAR() do { __builtin_amdgcn_sched_barrier(0); \
                    __builtin_amdgcn_s_barrier(); \
                    __builtin_amdgcn_sched_barrier(0); } while (0)

// ---------------------------------------------------------------------------
// Kernel 1: x = in + roll(in); LayerNorm over C=512; write bf16 normed.
// ---------------------------------------------------------------------------
__global__ __launch_bounds__(128)
void ln_kernel(const float* __restrict__ in, const float* __restrict__ gamma,
               const float* __restrict__ beta, ushort* __restrict__ normed) {
    const int row = blockIdx.x;
    const int t = threadIdx.x;
    const int row2 = rolled_row(row);

    const float4* p0 = (const float4*)(in + (size_t)row * 512);
    const float4* p1 = (const float4*)(in + (size_t)row2 * 512);
    float4 a = p0[t], c = p1[t];
    float x0 = a.x + c.x, x1 = a.y + c.y, x2 = a.z + c.z, x3 = a.w + c.w;

    float s = x0 + x1 + x2 + x3;
    float sq = x0 * x0 + x1 * x1 + x2 * x2 + x3 * x3;
#pragma unroll
    for (int o = 32; o > 0; o >>= 1) {
        s += __shfl_xor(s, o);
        sq += __shfl_xor(sq, o);
    }
    __shared__ float red[4];
    if ((t & 63) == 0) { red[(t >> 6) * 2] = s; red[(t >> 6) * 2 + 1] = sq; }
    __syncthreads();
    s = red[0] + red[2];
    sq = red[1] + red[3];
    float mu = s * (1.0f / 512.0f);
    float var = sq * (1.0f / 512.0f) - mu * mu;
    float rs = rsqrtf(var + 1e-6f);

    float4 g = ((const float4*)gamma)[t];
    float4 be = ((const float4*)beta)[t];
    ushort4 o4;
    o4.x = f2bf((x0 - mu) * rs * g.x + be.x);
    o4.y = f2bf((x1 - mu) * rs * g.y + be.y);
    o4.z = f2bf((x2 - mu) * rs * g.z + be.z);
    o4.w = f2bf((x3 - mu) * rs * g.w + be.w);
    ((ushort4*)(normed + (size_t)row * 512))[t] = o4;
}

// ---------------------------------------------------------------------------
// Kernel 2: transpose + cast fp32 [R][Ccols] -> bf16 [Ccols][R]
// ---------------------------------------------------------------------------
__global__ __launch_bounds__(256)
void transpose_cast(const float* __restrict__ src, ushort* __restrict__ dst,
                    int R, int Ccols) {
    __shared__ float tile[32][33];
    const int bx = blockIdx.x * 32;
    const int by = blockIdx.y * 32;
    const int tx = threadIdx.x, ty = threadIdx.y;
#pragma unroll
    for (int i = 0; i < 32; i += 8)
        tile[ty + i][tx] = src[(size_t)(by + ty + i) * Ccols + bx + tx];
    __syncthreads();
#pragma unroll
    for (int i = 0; i < 32; i += 8)
        dst[(size_t)(bx + ty + i) * R + by + tx] = f2bf(tile[tx][ty + i]);
}

// ---------------------------------------------------------------------------
// Persistent 8-phase 256x256 GEMM.  C = A[M,KT] * Bt[N,KT]^T, bf16/f32-acc.
// 512 thr = 8 waves (2M x 4N), per-wave C = 128x64 (8x4 16x16 frags).
// GROUPS output tiles per block (same bcol, brow = brow0 + g*256), linear
// K-tile stream T in [0, GROUPS*KT/64) with a 4-slot ring per matrix
// (slot = ((T&1)<<1)|kh), counted vmcnt(6) at tile boundaries only.
// Epilogue per group: direct global stores (no LDS), placed after the
// boundary barrier so stores drain under the next tile's compute.
// ---------------------------------------------------------------------------
template <int EPI, int GROUPS, int KT, int LOG2NCB>
__global__ __launch_bounds__(512, 2)
void gemm8p(const ushort* __restrict__ A, const ushort* __restrict__ Bt,
            const float* __restrict__ bias, const float* __restrict__ resid,
            ushort* __restrict__ outH, float* __restrict__ outF, int N) {
    constexpr unsigned NT_L = KT / 64;
    constexpr int TT = GROUPS * (int)NT_L;   // = 32 for both GEMMs
    __shared__ __align__(16) char sm[131072];
    const int t = threadIdx.x;
    const int w = t >> 6, l = t & 63;
    const int wr = w >> 2, wc = w & 3;

    // XCD-aware bijective swizzle (nwg = 256, divisible by 8)
    const int nwg = gridDim.x;
    const int bid = blockIdx.x;
    const int swz = (bid & 7) * (nwg >> 3) + (bid >> 3);
    const int cb = swz & ((1 << LOG2NCB) - 1);
    const int rgrp = swz >> LOG2NCB;
    const int brow0 = rgrp * (GROUPS * 256);
    const int bcol = cb << 8;

    // staging source (per thread); k-chunk pre-swizzled (inverse of read XOR)
    const int kksw = (((t & 3) ^ ((t >> 4) & 3)) << 3);
    const size_t aTh = (size_t)(t >> 2) * KT + kksw;
    const size_t bTh = (size_t)(bcol + (t >> 2)) * KT + kksw;
    const ushort* const aPanel = A + (size_t)brow0 * KT;
    char* const dA = (char*)sm + (w << 10);   // wave-uniform dest base
    char* const dB = dA + 65536;

    // fragment ds_read offsets: byte = row*64 + (l>>4)*16, XOR-swizzled
    const int xorv = ((l >> 2) & 3) << 4;
    const int preA = ((((wr << 7) + (l & 15)) << 6) + ((l >> 4) << 4)) ^ xorv;
    const int preB = 65536 + (((((wc << 6) + (l & 15)) << 6) + ((l >> 4) << 4)) ^ xorv);

    f32x4 acc[8][4] = {};
    bf16x8 aF[4], bF[4];

    auto issueA = [&](int T, int kh) {
        const int slot = ((T & 1) << 1) | kh;
        const unsigned g = (unsigned)T / NT_L, lt = (unsigned)T % NT_L;
        const ushort* s = aPanel + aTh + (size_t)g * (256u * KT) + lt * 64 + kh * 32;
        char* d = dA + (slot << 14);
        __builtin_amdgcn_global_load_lds(GLOBAL_AS(s), LDS_AS(d), 16, 0, 0);
        __builtin_amdgcn_global_load_lds(GLOBAL_AS(s + (size_t)128 * KT), LDS_AS(d + 8192), 16, 0, 0);
    };
    auto issueB = [&](int T, int kh) {
        const int slot = ((T & 1) << 1) | kh;
        const unsigned lt = (unsigned)T % NT_L;
        const ushort* s = Bt + bTh + lt * 64 + kh * 32;
        char* d = dB + (slot << 14);
        __builtin_amdgcn_global_load_lds(GLOBAL_AS(s), LDS_AS(d), 16, 0, 0);
        __builtin_amdgcn_global_load_lds(GLOBAL_AS(s + (size_t)128 * KT), LDS_AS(d + 8192), 16, 0, 0);
    };
    auto rdA = [&](int slot, int mb) {
        const char* p = (const char*)sm + (slot << 14) + preA + (mb << 12);
        aF[0] = *(const bf16x8*)(p);
        aF[1] = *(const bf16x8*)(p + 1024);
        aF[2] = *(const bf16x8*)(p + 2048);
        aF[3] = *(const bf16x8*)(p + 3072);
    };
    auto rdB = [&](int slot) {
        const char* p = (const char*)sm + (slot << 14) + preB;
        bF[0] = *(const bf16x8*)(p);
        bF[1] = *(const bf16x8*)(p + 1024);
        bF[2] = *(const bf16x8*)(p + 2048);
        bF[3] = *(const bf16x8*)(p + 3072);
    };
    auto mfma16 = [&](int mb) {
        __builtin_amdgcn_s_setprio(1);
#pragma unroll
        for (int mf = 0; mf < 4; ++mf)
#pragma unroll
            for (int nf = 0; nf < 4; ++nf)
                acc[mb * 4 + mf][nf] = __builtin_amdgcn_mfma_f32_16x16x32_bf16(
                    aF[mf], bF[nf], acc[mb * 4 + mf][nf], 0, 0, 0);
        __builtin_amdgcn_s_setprio(0);
    };

    // per-block-constant bias fragment
    float bv[4];
#pragma unroll
    for (int nf = 0; nf < 4; ++nf)
        bv[nf] = bias[bcol + (wc << 6) + nf * 16 + (l & 15)];

    // LDS-free epilogue for output-tile group g; then zero acc.
    auto epilogue = [&](int g) {
        const int rbase = brow0 + g * 256 + (wr << 7) + ((l >> 4) << 2);
        const int cbase = bcol + (wc << 6) + (l & 15);
#pragma unroll
        for (int mf = 0; mf < 8; ++mf) {
#pragma unroll
            for (int r = 0; r < 4; ++r) {
                const int row = rbase + mf * 16 + r;
                if constexpr (EPI == 0) {
#pragma unroll
                    for (int nf = 0; nf < 4; ++nf)
                        outH[(size_t)row * N + cbase + nf * 16] =
                            f2bf(gelu_tanh(acc[mf][nf][r] + bv[nf]));
                } else {
                    const float* x0 = resid + (size_t)row * 512;
                    const float* x1 = resid + (size_t)rolled_row(row) * 512;
#pragma unroll
                    for (int nf = 0; nf < 4; ++nf) {
                        const int col = cbase + nf * 16;
                        outF[(size_t)row * N + col] =
                            acc[mf][nf][r] + bv[nf] + x0[col] + x1[col];
                    }
                }
            }
        }
#pragma unroll
        for (int mf = 0; mf < 8; ++mf)
#pragma unroll
            for (int nf = 0; nf < 4; ++nf)
                acc[mf][nf] = f32x4{0.f, 0.f, 0.f, 0.f};
    };

    // --- prologue: 7 units (tile 0 complete + 3 units of tile 1)
    issueA(0, 0); issueB(0, 0);
    issueA(0, 1); issueB(0, 1);
    issueA(1, 0); issueB(1, 0);
    issueA(1, 1);
    __builtin_amdgcn_sched_barrier(0);
    asm volatile("s_waitcnt vmcnt(6)" ::: "memory");
    SBAR();

#pragma unroll 1
    for (int T = 0; T < TT; ++T) {
        if (GROUPS > 1 && T > 0 && ((unsigned)T % NT_L) == 0)
            epilogue((int)((unsigned)T / NT_L) - 1);
        const int s0 = (T & 1) << 1;
        // phase 0: kh=0, m-frags 0-3; issue B(T+1, kh=1)
        rdA(s0, 0); rdB(s0);
        SBAR();
        if (T + 1 < TT) issueB(T + 1, 1);
        mfma16(0);
        SBAR();
        // phase 1: kh=0, m-frags 4-7 (reuse bF); issue A(T+2, kh=0)
        rdA(s0, 1);
        SBAR();
        if (T + 2 < TT) issueA(T + 2, 0);
        mfma16(1);
        SBAR();
        // phase 2: kh=1, m-frags 0-3; issue B(T+2, kh=0)
        rdA(s0 + 1, 0); rdB(s0 + 1);
        SBAR();
        if (T + 2 < TT) issueB(T + 2, 0);
        mfma16(0);
        SBAR();
        // phase 3: kh=1, m-frags 4-7; issue A(T+2, kh=1)
        rdA(s0 + 1, 1);
        SBAR();
        if (T + 2 < TT) issueA(T + 2, 1);
        mfma16(1);
        __builtin_amdgcn_sched_barrier(0);
        if (T < TT - 2)       { asm volatile("s_waitcnt vmcnt(6)" ::: "memory"); }
        else if (T == TT - 2) { asm volatile("s_waitcnt vmcnt(0)" ::: "memory"); }
        SBAR();   // publish next tile's units
    }
    epilogue(GROUPS - 1);
}

// ---------------------------------------------------------------------------
extern "C" void kernel_launch(void* const* d_in, const int* in_sizes, int n_in,
                              void* d_out, int out_size, void* d_ws, size_t ws_size,
                              hipStream_t stream) {
    const float* in = (const float*)d_in[0];
    const float* ln_g = (const float*)d_in[1];
    const float* ln_b = (const float*)d_in[2];
    const float* W1 = (const float*)d_in[3];
    const float* b1 = (const float*)d_in[4];
    const float* W2 = (const float*)d_in[5];
    const float* b2 = (const float*)d_in[6];
    float* out = (float*)d_out;

    char* ws = (char*)d_ws;
    ushort* normed = (ushort*)ws;                                  // 32 MB
    ushort* hbuf   = (ushort*)(ws + (size_t)32 * 1024 * 1024);     // 128 MB
    ushort* W1T    = (ushort*)(ws + (size_t)160 * 1024 * 1024);    // 2 MB [2048][512]
    ushort* W2T    = (ushort*)(ws + (size_t)162 * 1024 * 1024);    // 2 MB [512][2048]

    const int M = 32768;
    const int C = 512, C4 = 2048;

    ln_kernel<<<M, 128, 0, stream>>>(in, ln_g, ln_b, normed);
    transpose_cast<<<dim3(C4 / 32, C / 32), dim3(32, 8), 0, stream>>>(W1, W1T, C, C4);
    transpose_cast<<<dim3(C / 32, C4 / 32), dim3(32, 8), 0, stream>>>(W2, W2T, C4, C);

    // GEMM1: [32768,512]x[512,2048] -> gelu -> bf16 h. 256 blocks x 4 tiles.
    gemm8p<0, 4, 512, 3><<<dim3(256), 512, 0, stream>>>(
        normed, W1T, b1, nullptr, hbuf, nullptr, C4);
    // GEMM2: [32768,2048]x[2048,512] + bias + x -> out. 256 blocks x 1 tile.
    gemm8p<1, 1, 2048, 1><<<dim3(256), 512, 0, stream>>>(
        hbuf, W2T, b2, in, nullptr, out, C);
}